// Round 15
// baseline (1836.994 us; speedup 1.0000x reference)
//
#include <hip/hip_runtime.h>

using u16 = unsigned short;
using u32 = unsigned int;
using u64 = unsigned long long;
typedef __attribute__((ext_vector_type(8))) short bf16x8;
typedef __attribute__((ext_vector_type(4))) float f32x4;

#define B_ 32
#define T_ 128
#define E_ 512
#define H_ 1024
#define V_ 32000
#define NROW 4096
#define BTV ((size_t)B_ * T_ * V_)
#define NREC 32                   // recurrence blocks (R3-proven config)
#define NWK 128                   // static GEMM workers (R15: 224 -> 128, ONE variable)
#define GRID_MEGA (NREC + NWK)    // 160 <= 256 floor: all resident, any order
#define NTN 250                   // logits n-tiles (32000/128)
#define NTILES (32 * NTN)         // 8000 logits tiles (m-major)
#define NT_STRIDE 256

#define AGENT __HIP_MEMORY_SCOPE_AGENT
#define RLX __ATOMIC_RELAXED

__device__ __forceinline__ u16 f2bf(float f) {
  u32 x = __float_as_uint(f);
  x += 0x7FFFu + ((x >> 16) & 1u);
  return (u16)(x >> 16);
}

__device__ __forceinline__ void gload_lds16(const void* g, void* l) {
  __builtin_amdgcn_global_load_lds(
      (const __attribute__((address_space(1))) u32*)g,
      (__attribute__((address_space(3))) u32*)l, 16, 0, 0);
}

__device__ __forceinline__ float sigm(float x) { return 1.f / (1.f + __expf(-x)); }

// ---------------- prep: f32 -> bf16 cast (vectorized) ----------------
__global__ void cast_bf16_kernel(const float* __restrict__ src, u16* __restrict__ dst, int n4) {
  int i = blockIdx.x * blockDim.x + threadIdx.x;
  int stride = gridDim.x * blockDim.x;
  for (; i < n4; i += stride) {
    float4 v = reinterpret_cast<const float4*>(src)[i];
    u32 p0 = (u32)f2bf(v.x) | ((u32)f2bf(v.y) << 16);
    u32 p1 = (u32)f2bf(v.z) | ((u32)f2bf(v.w) << 16);
    reinterpret_cast<uint2*>(dst)[i] = make_uint2(p0, p1);
  }
}

// ---------------- prep: X = bf16(relu(emb[tok])), rows r=b*128+t ----------------
__global__ void embed_kernel(const int* __restrict__ tgt, const float* __restrict__ emb,
                             u16* __restrict__ X) {
  int r = blockIdx.x * 2 + (threadIdx.x >> 7);  // 0..4095
  int c = threadIdx.x & 127;
  int t = r & 127;
  int tok = (t == 0) ? 1 : tgt[r - 1];          // BOS=1 ; tgt[b*128 + (t-1)]
  float4 v = reinterpret_cast<const float4*>(emb + (size_t)tok * E_)[c];
  u32 p0 = (u32)f2bf(fmaxf(v.x, 0.f)) | ((u32)f2bf(fmaxf(v.y, 0.f)) << 16);
  u32 p1 = (u32)f2bf(fmaxf(v.z, 0.f)) | ((u32)f2bf(fmaxf(v.w, 0.f)) << 16);
  reinterpret_cast<uint2*>(X + (size_t)r * E_)[c] = make_uint2(p0, p1);
}

// ---------------- Gi GEMM: C[4096][3072] = X @ W_ih^T + b_ih (m97 structure) -------
__global__ __launch_bounds__(256)
void gemm_bt_kernel(const u16* __restrict__ A, const u16* __restrict__ B,
                    const float* __restrict__ bias, float* __restrict__ C,
                    int K, int N) {
  __shared__ __align__(16) u16 As[128 * 32];
  __shared__ __align__(16) u16 Bs[128 * 32];
  int bid = blockIdx.x;
  int mtile = bid & 31, ntile = bid >> 5;
  int m0 = mtile << 7, n0 = ntile << 7;
  int tid = threadIdx.x, wv = tid >> 6, ln = tid & 63;
  int lr = ln & 15, lg = ln >> 4;
  int wrow = (wv >> 1) << 6, wcol = (wv & 1) << 6;

  f32x4 acc[4][4];
#pragma unroll
  for (int m = 0; m < 4; ++m)
#pragma unroll
    for (int n = 0; n < 4; ++n) acc[m][n] = (f32x4){0.f, 0.f, 0.f, 0.f};

  int c0 = tid, c1 = tid + 256;
  const u16* gA0 = A + (size_t)(m0 + (c0 >> 2)) * K + ((c0 & 3) << 3);
  const u16* gA1 = A + (size_t)(m0 + (c1 >> 2)) * K + ((c1 & 3) << 3);
  const u16* gB0 = B + (size_t)(n0 + (c0 >> 2)) * K + ((c0 & 3) << 3);
  const u16* gB1 = B + (size_t)(n0 + (c1 >> 2)) * K + ((c1 & 3) << 3);
  u16* lA0 = As + (wv << 9);
  u16* lA1 = As + 2048 + (wv << 9);
  u16* lB0 = Bs + (wv << 9);
  u16* lB1 = Bs + 2048 + (wv << 9);

  for (int k0 = 0; k0 < K; k0 += 32) {
    gload_lds16(gA0 + k0, lA0);
    gload_lds16(gA1 + k0, lA1);
    gload_lds16(gB0 + k0, lB0);
    gload_lds16(gB1 + k0, lB1);
    __syncthreads();
    bf16x8 a[4], b[4];
#pragma unroll
    for (int m = 0; m < 4; ++m)
      a[m] = *reinterpret_cast<const bf16x8*>(&As[(wrow + (m << 4) + lr) * 32 + (lg << 3)]);
#pragma unroll
    for (int n = 0; n < 4; ++n)
      b[n] = *reinterpret_cast<const bf16x8*>(&Bs[(wcol + (n << 4) + lr) * 32 + (lg << 3)]);
#pragma unroll
    for (int m = 0; m < 4; ++m)
#pragma unroll
      for (int n = 0; n < 4; ++n)
        acc[m][n] = __builtin_amdgcn_mfma_f32_16x16x32_bf16(a[m], b[n], acc[m][n], 0, 0, 0);
    __syncthreads();
  }

#pragma unroll
  for (int m = 0; m < 4; ++m) {
    int rowb = m0 + wrow + (m << 4) + (lg << 2);
#pragma unroll
    for (int n = 0; n < 4; ++n) {
      int col = n0 + wcol + (n << 4) + lr;
      float bvn = bias[col];
#pragma unroll
      for (int i = 0; i < 4; ++i)
        C[(size_t)(rowb + i) * N + col] = acc[m][n][i] + bvn;
    }
  }
}

// ---------------- MEGA: recur (32 blocks, R3 structure) + STATIC logits workers ----
// R14 structure verbatim (980 us mega, 1224 total, passed). ONE delta vs R14:
// NWK 224 -> 128 (halve instantaneous worker L3/HBM demand colliding with
// recur's latency chain; capacity still 2.4x recur's production rate).
// Deadlock audit: grid 160 <= 256 => all resident; recur waits on recur flags
// only (terminal 128 unconditional); workers wait on flags only. Static lists.
__global__ __launch_bounds__(256)
void mega_kernel(const u16* __restrict__ Whh16, const float* __restrict__ Gi,
                 const float* __restrict__ bhh, const float* __restrict__ enc_h,
                 u16* __restrict__ hb16, u16* __restrict__ Hall,
                 const u16* __restrict__ Wout16,
                 const float* __restrict__ bout, float* __restrict__ out,
                 float* __restrict__ pM, float* __restrict__ pS,
                 float* __restrict__ outTail, u32* __restrict__ flags) {
  __shared__ __align__(16) char smem[49152];   // union: recur red 49152 | worker 18432
  int bid = blockIdx.x, tid = threadIdx.x;
  int wv = tid >> 6, ln = tid & 63, lr = ln & 15, lg = ln >> 4;

  if (bid < NREC) {
    // ============ persistent GRU recurrence (R3-proven; Hall t-major sc1) ============
    int j0 = bid << 5;
    int kb = wv << 8;
    float (*red)[2][6][256] = (float(*)[2][6][256])smem;  // 49152 B exactly

    bf16x8 wf[6][8];
#pragma unroll
    for (int g = 0; g < 3; ++g)
#pragma unroll
      for (int nh = 0; nh < 2; ++nh) {
        const u16* wrow = Whh16 + (size_t)(g * H_ + j0 + nh * 16 + lr) * H_ + kb + (lg << 3);
#pragma unroll
        for (int kk = 0; kk < 8; ++kk)
          wf[g * 2 + nh][kk] = *reinterpret_cast<const bf16x8*>(wrow + kk * 32);
      }

    int bb = tid >> 3;
    int j4 = (tid & 7) << 2;
    float4 bhr = *reinterpret_cast<const float4*>(bhh + 0 * H_ + j0 + j4);
    float4 bhz = *reinterpret_cast<const float4*>(bhh + 1 * H_ + j0 + j4);
    float4 bhn = *reinterpret_cast<const float4*>(bhh + 2 * H_ + j0 + j4);
    float4 hp = *reinterpret_cast<const float4*>(enc_h + bb * H_ + j0 + j4);

    for (int t = 0; t < T_; ++t) {
      int cur = t & 1, nxt = cur ^ 1;

      const float* gib = Gi + (size_t)(bb * T_ + t) * (3 * H_) + j0 + j4;
      float4 gir = *reinterpret_cast<const float4*>(gib + 0 * H_);
      float4 giz = *reinterpret_cast<const float4*>(gib + 1 * H_);
      float4 gin = *reinterpret_cast<const float4*>(gib + 2 * H_);

      if (t > 0) {
        if (ln < 8) {
          while (__hip_atomic_load(&flags[(wv * 8 + ln) * 16], RLX, AGENT) < (u32)t)
            __builtin_amdgcn_s_sleep(1);
        }
      }

      const u16* hbase = hb16 + (size_t)cur * (B_ * H_) + kb + (lg << 3);
      f32x4 acc[2][6];
#pragma unroll
      for (int mt = 0; mt < 2; ++mt)
#pragma unroll
        for (int tn = 0; tn < 6; ++tn) acc[mt][tn] = (f32x4){0.f, 0.f, 0.f, 0.f};
#pragma unroll
      for (int kk = 0; kk < 8; ++kk) {
        const u64* p0 = reinterpret_cast<const u64*>(hbase + (size_t)lr * H_ + kk * 32);
        const u64* p1 = reinterpret_cast<const u64*>(hbase + (size_t)(16 + lr) * H_ + kk * 32);
        union { u64 q[2]; bf16x8 v; } A0, A1;
        A0.q[0] = __hip_atomic_load(p0, RLX, AGENT);
        A0.q[1] = __hip_atomic_load(p0 + 1, RLX, AGENT);
        A1.q[0] = __hip_atomic_load(p1, RLX, AGENT);
        A1.q[1] = __hip_atomic_load(p1 + 1, RLX, AGENT);
#pragma unroll
        for (int tn = 0; tn < 6; ++tn) {
          acc[0][tn] = __builtin_amdgcn_mfma_f32_16x16x32_bf16(A0.v, wf[tn][kk], acc[0][tn], 0, 0, 0);
          acc[1][tn] = __builtin_amdgcn_mfma_f32_16x16x32_bf16(A1.v, wf[tn][kk], acc[1][tn], 0, 0, 0);
        }
      }

#pragma unroll
      for (int mt = 0; mt < 2; ++mt)
#pragma unroll
        for (int tn = 0; tn < 6; ++tn)
#pragma unroll
          for (int i = 0; i < 4; ++i)
            red[wv][mt][tn][((lg << 2) + i) * 16 + lr] = acc[mt][tn][i];
      __syncthreads();

      int mt = bb >> 4;
      int nh = j4 >> 4;
      int rbase = (bb & 15) * 16 + (j4 & 15);
      float4 s[3];
#pragma unroll
      for (int g = 0; g < 3; ++g) {
        float4 a4 = make_float4(0.f, 0.f, 0.f, 0.f);
#pragma unroll
        for (int w = 0; w < 4; ++w) {
          float4 v = *reinterpret_cast<const float4*>(&red[w][mt][g * 2 + nh][rbase]);
          a4.x += v.x; a4.y += v.y; a4.z += v.z; a4.w += v.w;
        }
        s[g] = a4;
      }

      float hn[4];
      {
        float r0 = sigm(gir.x + s[0].x + bhr.x);
        float r1 = sigm(gir.y + s[0].y + bhr.y);
        float r2 = sigm(gir.z + s[0].z + bhr.z);
        float r3 = sigm(gir.w + s[0].w + bhr.w);
        float z0 = sigm(giz.x + s[1].x + bhz.x);
        float z1 = sigm(giz.y + s[1].y + bhz.y);
        float z2 = sigm(giz.z + s[1].z + bhz.z);
        float z3 = sigm(giz.w + s[1].w + bhz.w);
        float a0 = gin.x + r0 * (s[2].x + bhn.x);
        float a1 = gin.y + r1 * (s[2].y + bhn.y);
        float a2 = gin.z + r2 * (s[2].z + bhn.z);
        float a3 = gin.w + r3 * (s[2].w + bhn.w);
        float n0 = 2.f / (1.f + __expf(-2.f * a0)) - 1.f;
        float n1 = 2.f / (1.f + __expf(-2.f * a1)) - 1.f;
        float n2 = 2.f / (1.f + __expf(-2.f * a2)) - 1.f;
        float n3 = 2.f / (1.f + __expf(-2.f * a3)) - 1.f;
        hn[0] = (1.f - z0) * n0 + z0 * hp.x;
        hn[1] = (1.f - z1) * n1 + z1 * hp.y;
        hn[2] = (1.f - z2) * n2 + z2 * hp.z;
        hn[3] = (1.f - z3) * n3 + z3 * hp.w;
        hp = make_float4(hn[0], hn[1], hn[2], hn[3]);
      }

      u32 p0 = (u32)f2bf(hn[0]) | ((u32)f2bf(hn[1]) << 16);
      u32 p1 = (u32)f2bf(hn[2]) | ((u32)f2bf(hn[3]) << 16);
      u64 pv = (u64)p0 | ((u64)p1 << 32);

      // Hall t-major, agent-scope (intra-kernel consumers on other XCDs)
      __hip_atomic_store(reinterpret_cast<u64*>(Hall + (size_t)(t * B_ + bb) * H_ + j0 + j4),
                         pv, RLX, AGENT);
      if (t < T_ - 1) {
        __hip_atomic_store(reinterpret_cast<u64*>(hb16 + (size_t)nxt * (B_ * H_) + bb * H_ + j0 + j4),
                           pv, RLX, AGENT);
      } else {
        reinterpret_cast<float4*>(outTail + (size_t)bb * H_ + j0 + j4)[0] = hp;
      }
      __syncthreads();  // red reads done; vmcnt(0) drain -> Hall/h committed at L3
      if (tid == 0)
        __hip_atomic_store(&flags[bid * 16], (u32)(t + 1), RLX, AGENT);  // terminal: 128
    }
    return;
  }

  // ============ static logits GEMM workers: tiles tau = wid, wid+NWK, ... ============
  int wid = bid - NREC;
  u16* As = (u16*)smem;
  u16* Bs = (u16*)(smem + 8192);
  float* pmh = (float*)(smem + 16384);  // [2][128]
  float* psh = (float*)(smem + 17408);  // [2][128]
  int wrow = (wv >> 1) << 6, wcol = (wv & 1) << 6;

  for (int tau = wid; tau < NTILES; tau += NWK) {
    int m = tau / NTN, n = tau - m * NTN;
    int target = 4 * (m + 1);
    if (tid < NREC) {
      while ((int)__hip_atomic_load(&flags[tid * 16], RLX, AGENT) < target)
        __builtin_amdgcn_s_sleep(96);
    }
    __syncthreads();

    int m0 = m << 7, n0 = n << 7;
    f32x4 acc[4][4];
#pragma unroll
    for (int mi = 0; mi < 4; ++mi)
#pragma unroll
      for (int ni = 0; ni < 4; ++ni) acc[mi][ni] = (f32x4){0.f, 0.f, 0.f, 0.f};

    int c0 = tid, c1 = tid + 256;
    const u16* gA0 = Hall + (size_t)(m0 + (c0 >> 2)) * H_ + ((c0 & 3) << 3);
    const u16* gA1 = Hall + (size_t)(m0 + (c1 >> 2)) * H_ + ((c1 & 3) << 3);
    const u16* gB0 = Wout16 + (size_t)(n0 + (c0 >> 2)) * H_ + ((c0 & 3) << 3);
    const u16* gB1 = Wout16 + (size_t)(n0 + (c1 >> 2)) * H_ + ((c1 & 3) << 3);
    u16* lA0 = As + (wv << 9);
    u16* lA1 = As + 2048 + (wv << 9);
    u16* lB0 = Bs + (wv << 9);
    u16* lB1 = Bs + 2048 + (wv << 9);

    for (int k0 = 0; k0 < H_; k0 += 32) {
      gload_lds16(gA0 + k0, lA0);
      gload_lds16(gA1 + k0, lA1);
      gload_lds16(gB0 + k0, lB0);
      gload_lds16(gB1 + k0, lB1);
      __syncthreads();
      bf16x8 a[4], b[4];
#pragma unroll
      for (int mi = 0; mi < 4; ++mi)
        a[mi] = *reinterpret_cast<const bf16x8*>(&As[(wrow + (mi << 4) + lr) * 32 + (lg << 3)]);
#pragma unroll
      for (int ni = 0; ni < 4; ++ni)
        b[ni] = *reinterpret_cast<const bf16x8*>(&Bs[(wcol + (ni << 4) + lr) * 32 + (lg << 3)]);
#pragma unroll
      for (int mi = 0; mi < 4; ++mi)
#pragma unroll
        for (int ni = 0; ni < 4; ++ni)
          acc[mi][ni] = __builtin_amdgcn_mfma_f32_16x16x32_bf16(a[mi], b[ni], acc[mi][ni], 0, 0, 0);
      __syncthreads();
    }

    float bv[4];
#pragma unroll
    for (int ni = 0; ni < 4; ++ni) bv[ni] = bout[n0 + wcol + (ni << 4) + lr];

#pragma unroll
    for (int mi = 0; mi < 4; ++mi) {
#pragma unroll
      for (int i = 0; i < 4; ++i) {
        int row = wrow + (mi << 4) + (lg << 2) + i;
        int r = m0 + row;                            // t-major row
        int rg = (r & 31) * T_ + (r >> 5);           // b-major output row
        float* crow = out + (size_t)rg * V_;
        float v[4];
#pragma unroll
        for (int ni = 0; ni < 4; ++ni) {
          v[ni] = acc[mi][ni][i] + bv[ni];
          crow[n0 + wcol + (ni << 4) + lr] = v[ni];  // plain: consumed by later kernel
        }
        float vm = fmaxf(fmaxf(v[0], v[1]), fmaxf(v[2], v[3]));
        vm = fmaxf(vm, __shfl_xor(vm, 1));
        vm = fmaxf(vm, __shfl_xor(vm, 2));
        vm = fmaxf(vm, __shfl_xor(vm, 4));
        vm = fmaxf(vm, __shfl_xor(vm, 8));
        float se = __expf(v[0] - vm) + __expf(v[1] - vm) +
                   __expf(v[2] - vm) + __expf(v[3] - vm);
        se += __shfl_xor(se, 1);
        se += __shfl_xor(se, 2);
        se += __shfl_xor(se, 4);
        se += __shfl_xor(se, 8);
        if (lr == 0) { pmh[(wv & 1) * 128 + row] = vm; psh[(wv & 1) * 128 + row] = se; }
      }
    }
    __syncthreads();
    if (tid < 128) {
      float m0v = pmh[tid], m1v = pmh[128 + tid];
      float M = fmaxf(m0v, m1v);
      float S = psh[tid] * __expf(m0v - M) + psh[128 + tid] * __expf(m1v - M);
      int r = m0 + tid;
      int rg = (r & 31) * T_ + (r >> 5);
      pM[(size_t)rg * NT_STRIDE + n] = M;
      pS[(size_t)rg * NT_STRIDE + n] = S;
    }
    __syncthreads();  // pmh/psh reads done before next tile's writes
  }
}

// ---------------- fused LSE combine + subtract (512 threads/row) ----------------
__global__ __launch_bounds__(512)
void lse_fused_kernel(const float* __restrict__ pM, const float* __restrict__ pS,
                      float* __restrict__ out) {
  int r = blockIdx.x;
  int tid = threadIdx.x, wv = tid >> 6, ln = tid & 63;
  float M = -3.0e38f, S = 0.f;
  if (tid < NTN) { M = pM[(size_t)r * NT_STRIDE + tid]; S = pS[(size_t)r * NT_STRIDE + tid]; }
#pragma unroll
  for (int o = 32; o; o >>= 1) {
    float Mo = __shfl_xor(M, o);
    float So = __shfl_xor(S, o);
    float Mn = fmaxf(M, Mo);
    S = S * __expf(M - Mn) + So * __expf(Mo - Mn);
    M = Mn;
  }
  __shared__ float tM[8], tS[8], lsh;
  if (ln == 0) { tM[wv] = M; tS[wv] = S; }
  __syncthreads();
  if (tid == 0) {
    float Mf = tM[0], Sf = tS[0];
    for (int w = 1; w < 8; ++w) {
      float Mn = fmaxf(Mf, tM[w]);
      Sf = Sf * __expf(Mf - Mn) + tS[w] * __expf(tM[w] - Mn);
      Mf = Mn;
    }
    lsh = Mf + __logf(Sf);
  }
  __syncthreads();
  float l = lsh;
  float4* p = reinterpret_cast<float4*>(out + (size_t)r * V_);
  for (int i = tid; i < V_ / 4; i += 512) {
    float4 v = p[i];
    v.x -= l; v.y -= l; v.z -= l; v.w -= l;
    p[i] = v;
  }
}

// ---------------- host ----------------
extern "C" void kernel_launch(void* const* d_in, const int* in_sizes, int n_in,
                              void* d_out, int out_size, void* d_ws, size_t ws_size,
                              hipStream_t stream) {
  const float* enc_h = (const float*)d_in[1];
  const int*   tgt   = (const int*)d_in[2];
  const float* emb   = (const float*)d_in[3];
  const float* Wih   = (const float*)d_in[4];
  const float* Whh   = (const float*)d_in[5];
  const float* bih   = (const float*)d_in[6];
  const float* bhh   = (const float*)d_in[7];
  const float* Wout  = (const float*)d_in[8];
  const float* bout  = (const float*)d_in[9];
  float* out = (float*)d_out;

  char* ws = (char*)d_ws;
  size_t off = 0;
  auto alloc = [&](size_t bytes) -> void* {
    void* p = ws + off;
    off = (off + bytes + 255) & ~(size_t)255;
    return p;
  };
  u32*  flags  = (u32*)alloc(4096);
  u16*  Wih16  = (u16*)alloc((size_t)3 * H_ * E_ * 2);
  u16*  Whh16  = (u16*)alloc((size_t)3 * H_ * H_ * 2);
  u16*  Wout16 = (u16*)alloc((size_t)V_ * H_ * 2);
  u16*  X16    = (u16*)alloc((size_t)NROW * E_ * 2);
  u16*  Hall   = (u16*)alloc((size_t)NROW * H_ * 2);
  u16*  hb16   = (u16*)alloc((size_t)2 * B_ * H_ * 2);
  float* Gi    = (float*)alloc((size_t)NROW * 3 * H_ * 4);
  float* pM    = (float*)alloc((size_t)NROW * NT_STRIDE * 4);
  float* pS    = (float*)alloc((size_t)NROW * NT_STRIDE * 4);

  hipMemsetAsync(flags, 0, 4096, stream);
  cast_bf16_kernel<<<1024, 256, 0, stream>>>(Wih, Wih16, 3 * H_ * E_ / 4);
  cast_bf16_kernel<<<1024, 256, 0, stream>>>(Whh, Whh16, 3 * H_ * H_ / 4);
  cast_bf16_kernel<<<2048, 256, 0, stream>>>(Wout, Wout16, V_ * H_ / 4);
  cast_bf16_kernel<<<32, 256, 0, stream>>>(enc_h, hb16, B_ * H_ / 4);  // h buffer 0
  embed_kernel<<<NROW / 2, 256, 0, stream>>>(tgt, emb, X16);

  // Gi = X @ W_ih^T + b_ih   (M=4096, N=3072, K=512)
  gemm_bt_kernel<<<(3 * H_ / 128) * 32, 256, 0, stream>>>(X16, Wih16, bih, Gi, E_, 3 * H_);

  // recur + overlapped logits GEMM (static partition) in one dispatch
  mega_kernel<<<GRID_MEGA, 256, 0, stream>>>(Whh16, Gi, bhh, enc_h, hb16, Hall,
                                             Wout16, bout, out, pM, pS,
                                             out + BTV, flags);

  lse_fused_kernel<<<NROW, 512, 0, stream>>>(pM, pS, out);
}

// Round 16
// 1381.285 us; speedup vs baseline: 1.3299x; 1.3299x over previous
//
#include <hip/hip_runtime.h>

using u16 = unsigned short;
using u32 = unsigned int;
using u64 = unsigned long long;
typedef __attribute__((ext_vector_type(8))) short bf16x8;
typedef __attribute__((ext_vector_type(4))) float f32x4;

#define B_ 32
#define T_ 128
#define E_ 512
#define H_ 1024
#define V_ 32000
#define NROW 4096
#define BTV ((size_t)B_ * T_ * V_)
#define NREC 32                   // recurrence blocks (R3-proven config)
#define NWK 224                   // static GEMM workers (R15 proved 128 is worse)
#define GRID_MEGA (NREC + NWK)    // 256 = 1 block/CU floor: all resident, any order
#define NTN 250                   // logits n-tiles (32000/128)
#define NTILES (32 * NTN)         // 8000 logits tiles (m-major)
#define NT_STRIDE 256

#define AGENT __HIP_MEMORY_SCOPE_AGENT
#define RLX __ATOMIC_RELAXED

__device__ __forceinline__ u16 f2bf(float f) {
  u32 x = __float_as_uint(f);
  x += 0x7FFFu + ((x >> 16) & 1u);
  return (u16)(x >> 16);
}

__device__ __forceinline__ void gload_lds16(const void* g, void* l) {
  __builtin_amdgcn_global_load_lds(
      (const __attribute__((address_space(1))) u32*)g,
      (__attribute__((address_space(3))) u32*)l, 16, 0, 0);
}

__device__ __forceinline__ float sigm(float x) { return 1.f / (1.f + __expf(-x)); }

// ---------------- prep: f32 -> bf16 cast (vectorized) ----------------
__global__ void cast_bf16_kernel(const float* __restrict__ src, u16* __restrict__ dst, int n4) {
  int i = blockIdx.x * blockDim.x + threadIdx.x;
  int stride = gridDim.x * blockDim.x;
  for (; i < n4; i += stride) {
    float4 v = reinterpret_cast<const float4*>(src)[i];
    u32 p0 = (u32)f2bf(v.x) | ((u32)f2bf(v.y) << 16);
    u32 p1 = (u32)f2bf(v.z) | ((u32)f2bf(v.w) << 16);
    reinterpret_cast<uint2*>(dst)[i] = make_uint2(p0, p1);
  }
}

// ---------------- prep: X = bf16(relu(emb[tok])), rows r=b*128+t ----------------
__global__ void embed_kernel(const int* __restrict__ tgt, const float* __restrict__ emb,
                             u16* __restrict__ X) {
  int r = blockIdx.x * 2 + (threadIdx.x >> 7);  // 0..4095
  int c = threadIdx.x & 127;
  int t = r & 127;
  int tok = (t == 0) ? 1 : tgt[r - 1];          // BOS=1 ; tgt[b*128 + (t-1)]
  float4 v = reinterpret_cast<const float4*>(emb + (size_t)tok * E_)[c];
  u32 p0 = (u32)f2bf(fmaxf(v.x, 0.f)) | ((u32)f2bf(fmaxf(v.y, 0.f)) << 16);
  u32 p1 = (u32)f2bf(fmaxf(v.z, 0.f)) | ((u32)f2bf(fmaxf(v.w, 0.f)) << 16);
  reinterpret_cast<uint2*>(X + (size_t)r * E_)[c] = make_uint2(p0, p1);
}

// ---------------- Gi GEMM: C[4096][3072] = X @ W_ih^T + b_ih (m97 structure) -------
__global__ __launch_bounds__(256)
void gemm_bt_kernel(const u16* __restrict__ A, const u16* __restrict__ B,
                    const float* __restrict__ bias, float* __restrict__ C,
                    int K, int N) {
  __shared__ __align__(16) u16 As[128 * 32];
  __shared__ __align__(16) u16 Bs[128 * 32];
  int bid = blockIdx.x;
  int mtile = bid & 31, ntile = bid >> 5;
  int m0 = mtile << 7, n0 = ntile << 7;
  int tid = threadIdx.x, wv = tid >> 6, ln = tid & 63;
  int lr = ln & 15, lg = ln >> 4;
  int wrow = (wv >> 1) << 6, wcol = (wv & 1) << 6;

  f32x4 acc[4][4];
#pragma unroll
  for (int m = 0; m < 4; ++m)
#pragma unroll
    for (int n = 0; n < 4; ++n) acc[m][n] = (f32x4){0.f, 0.f, 0.f, 0.f};

  int c0 = tid, c1 = tid + 256;
  const u16* gA0 = A + (size_t)(m0 + (c0 >> 2)) * K + ((c0 & 3) << 3);
  const u16* gA1 = A + (size_t)(m0 + (c1 >> 2)) * K + ((c1 & 3) << 3);
  const u16* gB0 = B + (size_t)(n0 + (c0 >> 2)) * K + ((c0 & 3) << 3);
  const u16* gB1 = B + (size_t)(n0 + (c1 >> 2)) * K + ((c1 & 3) << 3);
  u16* lA0 = As + (wv << 9);
  u16* lA1 = As + 2048 + (wv << 9);
  u16* lB0 = Bs + (wv << 9);
  u16* lB1 = Bs + 2048 + (wv << 9);

  for (int k0 = 0; k0 < K; k0 += 32) {
    gload_lds16(gA0 + k0, lA0);
    gload_lds16(gA1 + k0, lA1);
    gload_lds16(gB0 + k0, lB0);
    gload_lds16(gB1 + k0, lB1);
    __syncthreads();
    bf16x8 a[4], b[4];
#pragma unroll
    for (int m = 0; m < 4; ++m)
      a[m] = *reinterpret_cast<const bf16x8*>(&As[(wrow + (m << 4) + lr) * 32 + (lg << 3)]);
#pragma unroll
    for (int n = 0; n < 4; ++n)
      b[n] = *reinterpret_cast<const bf16x8*>(&Bs[(wcol + (n << 4) + lr) * 32 + (lg << 3)]);
#pragma unroll
    for (int m = 0; m < 4; ++m)
#pragma unroll
      for (int n = 0; n < 4; ++n)
        acc[m][n] = __builtin_amdgcn_mfma_f32_16x16x32_bf16(a[m], b[n], acc[m][n], 0, 0, 0);
    __syncthreads();
  }

#pragma unroll
  for (int m = 0; m < 4; ++m) {
    int rowb = m0 + wrow + (m << 4) + (lg << 2);
#pragma unroll
    for (int n = 0; n < 4; ++n) {
      int col = n0 + wcol + (n << 4) + lr;
      float bvn = bias[col];
#pragma unroll
      for (int i = 0; i < 4; ++i)
        C[(size_t)(rowb + i) * N + col] = acc[m][n][i] + bvn;
    }
  }
}

// ---------------- MEGA: recur (R3 structure) + STATIC logits workers, BK=128 -------
// R14 structure (980 us mega, 1224 total). ONE mechanism change vs R14: worker
// K-step 32 -> 128 (8 outer iters instead of 32; same bytes staged; cuts the
// per-iter un-hidden vmcnt(0) latency stall 4x -- R15 showed workers at 1
// block/CU are latency-bound at ~27us/tile and ARE the binding resource).
// smem union grows 49152 -> 67584 (worker A 32K + B 32K + partials 2K).
// Deadlock audit unchanged: grid 256 all resident; recur<-flags; workers<-flags.
__global__ __launch_bounds__(256)
void mega_kernel(const u16* __restrict__ Whh16, const float* __restrict__ Gi,
                 const float* __restrict__ bhh, const float* __restrict__ enc_h,
                 u16* __restrict__ hb16, u16* __restrict__ Hall,
                 const u16* __restrict__ Wout16,
                 const float* __restrict__ bout, float* __restrict__ out,
                 float* __restrict__ pM, float* __restrict__ pS,
                 float* __restrict__ outTail, u32* __restrict__ flags) {
  __shared__ __align__(16) char smem[67584];   // union: recur 49152 | worker 67584
  int bid = blockIdx.x, tid = threadIdx.x;
  int wv = tid >> 6, ln = tid & 63, lr = ln & 15, lg = ln >> 4;

  if (bid < NREC) {
    // ============ persistent GRU recurrence (R3-proven; Hall t-major sc1) ============
    int j0 = bid << 5;
    int kb = wv << 8;
    float (*red)[2][6][256] = (float(*)[2][6][256])smem;  // uses first 49152 B

    bf16x8 wf[6][8];
#pragma unroll
    for (int g = 0; g < 3; ++g)
#pragma unroll
      for (int nh = 0; nh < 2; ++nh) {
        const u16* wrow = Whh16 + (size_t)(g * H_ + j0 + nh * 16 + lr) * H_ + kb + (lg << 3);
#pragma unroll
        for (int kk = 0; kk < 8; ++kk)
          wf[g * 2 + nh][kk] = *reinterpret_cast<const bf16x8*>(wrow + kk * 32);
      }

    int bb = tid >> 3;
    int j4 = (tid & 7) << 2;
    float4 bhr = *reinterpret_cast<const float4*>(bhh + 0 * H_ + j0 + j4);
    float4 bhz = *reinterpret_cast<const float4*>(bhh + 1 * H_ + j0 + j4);
    float4 bhn = *reinterpret_cast<const float4*>(bhh + 2 * H_ + j0 + j4);
    float4 hp = *reinterpret_cast<const float4*>(enc_h + bb * H_ + j0 + j4);

    for (int t = 0; t < T_; ++t) {
      int cur = t & 1, nxt = cur ^ 1;

      const float* gib = Gi + (size_t)(bb * T_ + t) * (3 * H_) + j0 + j4;
      float4 gir = *reinterpret_cast<const float4*>(gib + 0 * H_);
      float4 giz = *reinterpret_cast<const float4*>(gib + 1 * H_);
      float4 gin = *reinterpret_cast<const float4*>(gib + 2 * H_);

      if (t > 0) {
        if (ln < 8) {
          while (__hip_atomic_load(&flags[(wv * 8 + ln) * 16], RLX, AGENT) < (u32)t)
            __builtin_amdgcn_s_sleep(1);
        }
      }

      const u16* hbase = hb16 + (size_t)cur * (B_ * H_) + kb + (lg << 3);
      f32x4 acc[2][6];
#pragma unroll
      for (int mt = 0; mt < 2; ++mt)
#pragma unroll
        for (int tn = 0; tn < 6; ++tn) acc[mt][tn] = (f32x4){0.f, 0.f, 0.f, 0.f};
#pragma unroll
      for (int kk = 0; kk < 8; ++kk) {
        const u64* p0 = reinterpret_cast<const u64*>(hbase + (size_t)lr * H_ + kk * 32);
        const u64* p1 = reinterpret_cast<const u64*>(hbase + (size_t)(16 + lr) * H_ + kk * 32);
        union { u64 q[2]; bf16x8 v; } A0, A1;
        A0.q[0] = __hip_atomic_load(p0, RLX, AGENT);
        A0.q[1] = __hip_atomic_load(p0 + 1, RLX, AGENT);
        A1.q[0] = __hip_atomic_load(p1, RLX, AGENT);
        A1.q[1] = __hip_atomic_load(p1 + 1, RLX, AGENT);
#pragma unroll
        for (int tn = 0; tn < 6; ++tn) {
          acc[0][tn] = __builtin_amdgcn_mfma_f32_16x16x32_bf16(A0.v, wf[tn][kk], acc[0][tn], 0, 0, 0);
          acc[1][tn] = __builtin_amdgcn_mfma_f32_16x16x32_bf16(A1.v, wf[tn][kk], acc[1][tn], 0, 0, 0);
        }
      }

#pragma unroll
      for (int mt = 0; mt < 2; ++mt)
#pragma unroll
        for (int tn = 0; tn < 6; ++tn)
#pragma unroll
          for (int i = 0; i < 4; ++i)
            red[wv][mt][tn][((lg << 2) + i) * 16 + lr] = acc[mt][tn][i];
      __syncthreads();

      int mt = bb >> 4;
      int nh = j4 >> 4;
      int rbase = (bb & 15) * 16 + (j4 & 15);
      float4 s[3];
#pragma unroll
      for (int g = 0; g < 3; ++g) {
        float4 a4 = make_float4(0.f, 0.f, 0.f, 0.f);
#pragma unroll
        for (int w = 0; w < 4; ++w) {
          float4 v = *reinterpret_cast<const float4*>(&red[w][mt][g * 2 + nh][rbase]);
          a4.x += v.x; a4.y += v.y; a4.z += v.z; a4.w += v.w;
        }
        s[g] = a4;
      }

      float hn[4];
      {
        float r0 = sigm(gir.x + s[0].x + bhr.x);
        float r1 = sigm(gir.y + s[0].y + bhr.y);
        float r2 = sigm(gir.z + s[0].z + bhr.z);
        float r3 = sigm(gir.w + s[0].w + bhr.w);
        float z0 = sigm(giz.x + s[1].x + bhz.x);
        float z1 = sigm(giz.y + s[1].y + bhz.y);
        float z2 = sigm(giz.z + s[1].z + bhz.z);
        float z3 = sigm(giz.w + s[1].w + bhz.w);
        float a0 = gin.x + r0 * (s[2].x + bhn.x);
        float a1 = gin.y + r1 * (s[2].y + bhn.y);
        float a2 = gin.z + r2 * (s[2].z + bhn.z);
        float a3 = gin.w + r3 * (s[2].w + bhn.w);
        float n0 = 2.f / (1.f + __expf(-2.f * a0)) - 1.f;
        float n1 = 2.f / (1.f + __expf(-2.f * a1)) - 1.f;
        float n2 = 2.f / (1.f + __expf(-2.f * a2)) - 1.f;
        float n3 = 2.f / (1.f + __expf(-2.f * a3)) - 1.f;
        hn[0] = (1.f - z0) * n0 + z0 * hp.x;
        hn[1] = (1.f - z1) * n1 + z1 * hp.y;
        hn[2] = (1.f - z2) * n2 + z2 * hp.z;
        hn[3] = (1.f - z3) * n3 + z3 * hp.w;
        hp = make_float4(hn[0], hn[1], hn[2], hn[3]);
      }

      u32 p0 = (u32)f2bf(hn[0]) | ((u32)f2bf(hn[1]) << 16);
      u32 p1 = (u32)f2bf(hn[2]) | ((u32)f2bf(hn[3]) << 16);
      u64 pv = (u64)p0 | ((u64)p1 << 32);

      // Hall t-major, agent-scope (intra-kernel consumers on other XCDs)
      __hip_atomic_store(reinterpret_cast<u64*>(Hall + (size_t)(t * B_ + bb) * H_ + j0 + j4),
                         pv, RLX, AGENT);
      if (t < T_ - 1) {
        __hip_atomic_store(reinterpret_cast<u64*>(hb16 + (size_t)nxt * (B_ * H_) + bb * H_ + j0 + j4),
                           pv, RLX, AGENT);
      } else {
        reinterpret_cast<float4*>(outTail + (size_t)bb * H_ + j0 + j4)[0] = hp;
      }
      __syncthreads();  // red reads done; vmcnt(0) drain -> Hall/h committed at L3
      if (tid == 0)
        __hip_atomic_store(&flags[bid * 16], (u32)(t + 1), RLX, AGENT);  // terminal: 128
    }
    return;
  }

  // ============ static logits GEMM workers, BK=128: tiles tau = wid, wid+NWK ... ====
  int wid = bid - NREC;
  u16* As = (u16*)smem;                 // [128][128] u16 = 32768 B
  u16* Bs = (u16*)(smem + 32768);       // 32768 B
  float* pmh = (float*)(smem + 65536);  // [2][128]
  float* psh = (float*)(smem + 66560);  // [2][128]
  int wrow = (wv >> 1) << 6, wcol = (wv & 1) << 6;

  for (int tau = wid; tau < NTILES; tau += NWK) {
    int m = tau / NTN, n = tau - m * NTN;
    int target = 4 * (m + 1);
    if (tid < NREC) {
      while ((int)__hip_atomic_load(&flags[tid * 16], RLX, AGENT) < target)
        __builtin_amdgcn_s_sleep(96);
    }
    __syncthreads();

    int m0 = m << 7, n0 = n << 7;
    f32x4 acc[4][4];
#pragma unroll
    for (int mi = 0; mi < 4; ++mi)
#pragma unroll
      for (int ni = 0; ni < 4; ++ni) acc[mi][ni] = (f32x4){0.f, 0.f, 0.f, 0.f};

    // staging: 2048 chunks/side of 16B; chunk c -> row c>>4, seg c&15;
    // thread stages c = i*256 + tid, i = 0..7 (rows advance 16 per issue)
    const u16* gA = Hall + (size_t)(m0 + (tid >> 4)) * H_ + ((tid & 15) << 3);
    const u16* gB = Wout16 + (size_t)(n0 + (tid >> 4)) * H_ + ((tid & 15) << 3);
    u16* lA = As + (wv << 9);           // wave-uniform base (HW adds lane*16B)
    u16* lB = Bs + (wv << 9);

    for (int k0 = 0; k0 < H_; k0 += 128) {
#pragma unroll
      for (int i = 0; i < 8; ++i) {
        gload_lds16(gA + (size_t)i * 16 * H_ + k0, lA + i * 2048);
        gload_lds16(gB + (size_t)i * 16 * H_ + k0, lB + i * 2048);
      }
      __syncthreads();
#pragma unroll
      for (int kk = 0; kk < 4; ++kk) {
        bf16x8 a[4], b[4];
#pragma unroll
        for (int mi = 0; mi < 4; ++mi)
          a[mi] = *reinterpret_cast<const bf16x8*>(
              &As[(wrow + (mi << 4) + lr) * 128 + (kk << 5) + (lg << 3)]);
#pragma unroll
        for (int ni = 0; ni < 4; ++ni)
          b[ni] = *reinterpret_cast<const bf16x8*>(
              &Bs[(wcol + (ni << 4) + lr) * 128 + (kk << 5) + (lg << 3)]);
#pragma unroll
        for (int mi = 0; mi < 4; ++mi)
#pragma unroll
          for (int ni = 0; ni < 4; ++ni)
            acc[mi][ni] = __builtin_amdgcn_mfma_f32_16x16x32_bf16(a[mi], b[ni], acc[mi][ni], 0, 0, 0);
      }
      __syncthreads();
    }

    float bv[4];
#pragma unroll
    for (int ni = 0; ni < 4; ++ni) bv[ni] = bout[n0 + wcol + (ni << 4) + lr];

#pragma unroll
    for (int mi = 0; mi < 4; ++mi) {
#pragma unroll
      for (int i = 0; i < 4; ++i) {
        int row = wrow + (mi << 4) + (lg << 2) + i;
        int r = m0 + row;                            // t-major row
        int rg = (r & 31) * T_ + (r >> 5);           // b-major output row
        float* crow = out + (size_t)rg * V_;
        float v[4];
#pragma unroll
        for (int ni = 0; ni < 4; ++ni) {
          v[ni] = acc[mi][ni][i] + bv[ni];
          crow[n0 + wcol + (ni << 4) + lr] = v[ni];  // plain: consumed by later kernel
        }
        float vm = fmaxf(fmaxf(v[0], v[1]), fmaxf(v[2], v[3]));
        vm = fmaxf(vm, __shfl_xor(vm, 1));
        vm = fmaxf(vm, __shfl_xor(vm, 2));
        vm = fmaxf(vm, __shfl_xor(vm, 4));
        vm = fmaxf(vm, __shfl_xor(vm, 8));
        float se = __expf(v[0] - vm) + __expf(v[1] - vm) +
                   __expf(v[2] - vm) + __expf(v[3] - vm);
        se += __shfl_xor(se, 1);
        se += __shfl_xor(se, 2);
        se += __shfl_xor(se, 4);
        se += __shfl_xor(se, 8);
        if (lr == 0) { pmh[(wv & 1) * 128 + row] = vm; psh[(wv & 1) * 128 + row] = se; }
      }
    }
    __syncthreads();
    if (tid < 128) {
      float m0v = pmh[tid], m1v = pmh[128 + tid];
      float M = fmaxf(m0v, m1v);
      float S = psh[tid] * __expf(m0v - M) + psh[128 + tid] * __expf(m1v - M);
      int r = m0 + tid;
      int rg = (r & 31) * T_ + (r >> 5);
      pM[(size_t)rg * NT_STRIDE + n] = M;
      pS[(size_t)rg * NT_STRIDE + n] = S;
    }
    __syncthreads();  // pmh/psh reads done before next tile's writes
  }
}

// ---------------- fused LSE combine + subtract (512 threads/row) ----------------
__global__ __launch_bounds__(512)
void lse_fused_kernel(const float* __restrict__ pM, const float* __restrict__ pS,
                      float* __restrict__ out) {
  int r = blockIdx.x;
  int tid = threadIdx.x, wv = tid >> 6, ln = tid & 63;
  float M = -3.0e38f, S = 0.f;
  if (tid < NTN) { M = pM[(size_t)r * NT_STRIDE + tid]; S = pS[(size_t)r * NT_STRIDE + tid]; }
#pragma unroll
  for (int o = 32; o; o >>= 1) {
    float Mo = __shfl_xor(M, o);
    float So = __shfl_xor(S, o);
    float Mn = fmaxf(M, Mo);
    S = S * __expf(M - Mn) + So * __expf(Mo - Mn);
    M = Mn;
  }
  __shared__ float tM[8], tS[8], lsh;
  if (ln == 0) { tM[wv] = M; tS[wv] = S; }
  __syncthreads();
  if (tid == 0) {
    float Mf = tM[0], Sf = tS[0];
    for (int w = 1; w < 8; ++w) {
      float Mn = fmaxf(Mf, tM[w]);
      Sf = Sf * __expf(Mf - Mn) + tS[w] * __expf(tM[w] - Mn);
      Mf = Mn;
    }
    lsh = Mf + __logf(Sf);
  }
  __syncthreads();
  float l = lsh;
  float4* p = reinterpret_cast<float4*>(out + (size_t)r * V_);
  for (int i = tid; i < V_ / 4; i += 512) {
    float4 v = p[i];
    v.x -= l; v.y -= l; v.z -= l; v.w -= l;
    p[i] = v;
  }
}

// ---------------- host ----------------
extern "C" void kernel_launch(void* const* d_in, const int* in_sizes, int n_in,
                              void* d_out, int out_size, void* d_ws, size_t ws_size,
                              hipStream_t stream) {
  const float* enc_h = (const float*)d_in[1];
  const int*   tgt   = (const int*)d_in[2];
  const float* emb   = (const float*)d_in[3];
  const float* Wih   = (const float*)d_in[4];
  const float* Whh   = (const float*)d_in[5];
  const float* bih   = (const float*)d_in[6];
  const float* bhh   = (const float*)d_in[7];
  const float* Wout  = (const float*)d_in[8];
  const float* bout  = (const float*)d_in[9];
  float* out = (float*)d_out;

  char* ws = (char*)d_ws;
  size_t off = 0;
  auto alloc = [&](size_t bytes) -> void* {
    void* p = ws + off;
    off = (off + bytes + 255) & ~(size_t)255;
    return p;
  };
  u32*  flags  = (u32*)alloc(4096);
  u16*  Wih16  = (u16*)alloc((size_t)3 * H_ * E_ * 2);
  u16*  Whh16  = (u16*)alloc((size_t)3 * H_ * H_ * 2);
  u16*  Wout16 = (u16*)alloc((size_t)V_ * H_ * 2);
  u16*  X16    = (u16*)alloc((size_t)NROW * E_ * 2);
  u16*  Hall   = (u16*)alloc((size_t)NROW * H_ * 2);
  u16*  hb16   = (u16*)alloc((size_t)2 * B_ * H_ * 2);
  float* Gi    = (float*)alloc((size_t)NROW * 3 * H_ * 4);
  float* pM    = (float*)alloc((size_t)NROW * NT_STRIDE * 4);
  float* pS    = (float*)alloc((size_t)NROW * NT_STRIDE * 4);

  hipMemsetAsync(flags, 0, 4096, stream);
  cast_bf16_kernel<<<1024, 256, 0, stream>>>(Wih, Wih16, 3 * H_ * E_ / 4);
  cast_bf16_kernel<<<1024, 256, 0, stream>>>(Whh, Whh16, 3 * H_ * H_ / 4);
  cast_bf16_kernel<<<2048, 256, 0, stream>>>(Wout, Wout16, V_ * H_ / 4);
  cast_bf16_kernel<<<32, 256, 0, stream>>>(enc_h, hb16, B_ * H_ / 4);  // h buffer 0
  embed_kernel<<<NROW / 2, 256, 0, stream>>>(tgt, emb, X16);

  // Gi = X @ W_ih^T + b_ih   (M=4096, N=3072, K=512)
  gemm_bt_kernel<<<(3 * H_ / 128) * 32, 256, 0, stream>>>(X16, Wih16, bih, Gi, E_, 3 * H_);

  // recur + overlapped logits GEMM (static partition, BK=128) in one dispatch
  mega_kernel<<<GRID_MEGA, 256, 0, stream>>>(Whh16, Gi, bhh, enc_h, hb16, Hall,
                                             Wout16, bout, out, pM, pS,
                                             out + BTV, flags);

  lse_fused_kernel<<<NROW, 512, 0, stream>>>(pM, pS, out);
}

// Round 17
// 1117.877 us; speedup vs baseline: 1.6433x; 1.2356x over previous
//
#include <hip/hip_runtime.h>

using u16 = unsigned short;
using u32 = unsigned int;
using u64 = unsigned long long;
typedef __attribute__((ext_vector_type(8))) short bf16x8;
typedef __attribute__((ext_vector_type(4))) float f32x4;

#define B_ 32
#define T_ 128
#define E_ 512
#define H_ 1024
#define V_ 32000
#define NROW 4096
#define BTV ((size_t)B_ * T_ * V_)
#define NREC 32                   // recurrence blocks (R3-proven config)
#define NWK 224                   // static GEMM workers
#define GRID_MEGA (NREC + NWK)    // 256 = 1 block/CU floor: all resident, any order
#define NTN 250                   // logits n-tiles (32000/128)
#define NTILES (32 * NTN)         // 8000 logits tiles (m-major)
#define NT_STRIDE 256

#define AGENT __HIP_MEMORY_SCOPE_AGENT
#define RLX __ATOMIC_RELAXED

__device__ __forceinline__ u16 f2bf(float f) {
  u32 x = __float_as_uint(f);
  x += 0x7FFFu + ((x >> 16) & 1u);
  return (u16)(x >> 16);
}

__device__ __forceinline__ void gload_lds16(const void* g, void* l) {
  __builtin_amdgcn_global_load_lds(
      (const __attribute__((address_space(1))) u32*)g,
      (__attribute__((address_space(3))) u32*)l, 16, 0, 0);
}

__device__ __forceinline__ float sigm(float x) { return 1.f / (1.f + __expf(-x)); }

// ---------------- prep: f32 -> bf16 cast (vectorized) ----------------
__global__ void cast_bf16_kernel(const float* __restrict__ src, u16* __restrict__ dst, int n4) {
  int i = blockIdx.x * blockDim.x + threadIdx.x;
  int stride = gridDim.x * blockDim.x;
  for (; i < n4; i += stride) {
    float4 v = reinterpret_cast<const float4*>(src)[i];
    u32 p0 = (u32)f2bf(v.x) | ((u32)f2bf(v.y) << 16);
    u32 p1 = (u32)f2bf(v.z) | ((u32)f2bf(v.w) << 16);
    reinterpret_cast<uint2*>(dst)[i] = make_uint2(p0, p1);
  }
}

// ---------------- prep: X = bf16(relu(emb[tok])), rows r=b*128+t ----------------
__global__ void embed_kernel(const int* __restrict__ tgt, const float* __restrict__ emb,
                             u16* __restrict__ X) {
  int r = blockIdx.x * 2 + (threadIdx.x >> 7);  // 0..4095
  int c = threadIdx.x & 127;
  int t = r & 127;
  int tok = (t == 0) ? 1 : tgt[r - 1];          // BOS=1 ; tgt[b*128 + (t-1)]
  float4 v = reinterpret_cast<const float4*>(emb + (size_t)tok * E_)[c];
  u32 p0 = (u32)f2bf(fmaxf(v.x, 0.f)) | ((u32)f2bf(fmaxf(v.y, 0.f)) << 16);
  u32 p1 = (u32)f2bf(fmaxf(v.z, 0.f)) | ((u32)f2bf(fmaxf(v.w, 0.f)) << 16);
  reinterpret_cast<uint2*>(X + (size_t)r * E_)[c] = make_uint2(p0, p1);
}

// ---------------- Gi GEMM: C[4096][3072] = X @ W_ih^T + b_ih (m97 structure) -------
__global__ __launch_bounds__(256)
void gemm_bt_kernel(const u16* __restrict__ A, const u16* __restrict__ B,
                    const float* __restrict__ bias, float* __restrict__ C,
                    int K, int N) {
  __shared__ __align__(16) u16 As[128 * 32];
  __shared__ __align__(16) u16 Bs[128 * 32];
  int bid = blockIdx.x;
  int mtile = bid & 31, ntile = bid >> 5;
  int m0 = mtile << 7, n0 = ntile << 7;
  int tid = threadIdx.x, wv = tid >> 6, ln = tid & 63;
  int lr = ln & 15, lg = ln >> 4;
  int wrow = (wv >> 1) << 6, wcol = (wv & 1) << 6;

  f32x4 acc[4][4];
#pragma unroll
  for (int m = 0; m < 4; ++m)
#pragma unroll
    for (int n = 0; n < 4; ++n) acc[m][n] = (f32x4){0.f, 0.f, 0.f, 0.f};

  int c0 = tid, c1 = tid + 256;
  const u16* gA0 = A + (size_t)(m0 + (c0 >> 2)) * K + ((c0 & 3) << 3);
  const u16* gA1 = A + (size_t)(m0 + (c1 >> 2)) * K + ((c1 & 3) << 3);
  const u16* gB0 = B + (size_t)(n0 + (c0 >> 2)) * K + ((c0 & 3) << 3);
  const u16* gB1 = B + (size_t)(n0 + (c1 >> 2)) * K + ((c1 & 3) << 3);
  u16* lA0 = As + (wv << 9);
  u16* lA1 = As + 2048 + (wv << 9);
  u16* lB0 = Bs + (wv << 9);
  u16* lB1 = Bs + 2048 + (wv << 9);

  for (int k0 = 0; k0 < K; k0 += 32) {
    gload_lds16(gA0 + k0, lA0);
    gload_lds16(gA1 + k0, lA1);
    gload_lds16(gB0 + k0, lB0);
    gload_lds16(gB1 + k0, lB1);
    __syncthreads();
    bf16x8 a[4], b[4];
#pragma unroll
    for (int m = 0; m < 4; ++m)
      a[m] = *reinterpret_cast<const bf16x8*>(&As[(wrow + (m << 4) + lr) * 32 + (lg << 3)]);
#pragma unroll
    for (int n = 0; n < 4; ++n)
      b[n] = *reinterpret_cast<const bf16x8*>(&Bs[(wcol + (n << 4) + lr) * 32 + (lg << 3)]);
#pragma unroll
    for (int m = 0; m < 4; ++m)
#pragma unroll
      for (int n = 0; n < 4; ++n)
        acc[m][n] = __builtin_amdgcn_mfma_f32_16x16x32_bf16(a[m], b[n], acc[m][n], 0, 0, 0);
    __syncthreads();
  }

#pragma unroll
  for (int m = 0; m < 4; ++m) {
    int rowb = m0 + wrow + (m << 4) + (lg << 2);
#pragma unroll
    for (int n = 0; n < 4; ++n) {
      int col = n0 + wcol + (n << 4) + lr;
      float bvn = bias[col];
#pragma unroll
      for (int i = 0; i < 4; ++i)
        C[(size_t)(rowb + i) * N + col] = acc[m][n][i] + bvn;
    }
  }
}

// ---------------- MEGA: recur (R3 structure) + workers BK=128 + XOR swizzle --------
// R16 + ONE fix: T2 LDS XOR swizzle on the worker tiles (rule #21 pattern:
// linear LDS dest + inverse-swizzled GLOBAL source + swizzled read).
// R16's [128][128] u16 tile read row-major was a 16-way bank conflict
// (SQ_LDS_BANK_CONFLICT 3.4e7 -> 2.3e8, ~375us). Swizzle: u16col ^= (row&7)<<3
// -> 16 fragment rows spread over 8 16B slots = 2-way = free (m136).
__global__ __launch_bounds__(256)
void mega_kernel(const u16* __restrict__ Whh16, const float* __restrict__ Gi,
                 const float* __restrict__ bhh, const float* __restrict__ enc_h,
                 u16* __restrict__ hb16, u16* __restrict__ Hall,
                 const u16* __restrict__ Wout16,
                 const float* __restrict__ bout, float* __restrict__ out,
                 float* __restrict__ pM, float* __restrict__ pS,
                 float* __restrict__ outTail, u32* __restrict__ flags) {
  __shared__ __align__(16) char smem[67584];   // union: recur 49152 | worker 67584
  int bid = blockIdx.x, tid = threadIdx.x;
  int wv = tid >> 6, ln = tid & 63, lr = ln & 15, lg = ln >> 4;

  if (bid < NREC) {
    // ============ persistent GRU recurrence (R3-proven; Hall t-major sc1) ============
    int j0 = bid << 5;
    int kb = wv << 8;
    float (*red)[2][6][256] = (float(*)[2][6][256])smem;  // uses first 49152 B

    bf16x8 wf[6][8];
#pragma unroll
    for (int g = 0; g < 3; ++g)
#pragma unroll
      for (int nh = 0; nh < 2; ++nh) {
        const u16* wrow = Whh16 + (size_t)(g * H_ + j0 + nh * 16 + lr) * H_ + kb + (lg << 3);
#pragma unroll
        for (int kk = 0; kk < 8; ++kk)
          wf[g * 2 + nh][kk] = *reinterpret_cast<const bf16x8*>(wrow + kk * 32);
      }

    int bb = tid >> 3;
    int j4 = (tid & 7) << 2;
    float4 bhr = *reinterpret_cast<const float4*>(bhh + 0 * H_ + j0 + j4);
    float4 bhz = *reinterpret_cast<const float4*>(bhh + 1 * H_ + j0 + j4);
    float4 bhn = *reinterpret_cast<const float4*>(bhh + 2 * H_ + j0 + j4);
    float4 hp = *reinterpret_cast<const float4*>(enc_h + bb * H_ + j0 + j4);

    for (int t = 0; t < T_; ++t) {
      int cur = t & 1, nxt = cur ^ 1;

      const float* gib = Gi + (size_t)(bb * T_ + t) * (3 * H_) + j0 + j4;
      float4 gir = *reinterpret_cast<const float4*>(gib + 0 * H_);
      float4 giz = *reinterpret_cast<const float4*>(gib + 1 * H_);
      float4 gin = *reinterpret_cast<const float4*>(gib + 2 * H_);

      if (t > 0) {
        if (ln < 8) {
          while (__hip_atomic_load(&flags[(wv * 8 + ln) * 16], RLX, AGENT) < (u32)t)
            __builtin_amdgcn_s_sleep(1);
        }
      }

      const u16* hbase = hb16 + (size_t)cur * (B_ * H_) + kb + (lg << 3);
      f32x4 acc[2][6];
#pragma unroll
      for (int mt = 0; mt < 2; ++mt)
#pragma unroll
        for (int tn = 0; tn < 6; ++tn) acc[mt][tn] = (f32x4){0.f, 0.f, 0.f, 0.f};
#pragma unroll
      for (int kk = 0; kk < 8; ++kk) {
        const u64* p0 = reinterpret_cast<const u64*>(hbase + (size_t)lr * H_ + kk * 32);
        const u64* p1 = reinterpret_cast<const u64*>(hbase + (size_t)(16 + lr) * H_ + kk * 32);
        union { u64 q[2]; bf16x8 v; } A0, A1;
        A0.q[0] = __hip_atomic_load(p0, RLX, AGENT);
        A0.q[1] = __hip_atomic_load(p0 + 1, RLX, AGENT);
        A1.q[0] = __hip_atomic_load(p1, RLX, AGENT);
        A1.q[1] = __hip_atomic_load(p1 + 1, RLX, AGENT);
#pragma unroll
        for (int tn = 0; tn < 6; ++tn) {
          acc[0][tn] = __builtin_amdgcn_mfma_f32_16x16x32_bf16(A0.v, wf[tn][kk], acc[0][tn], 0, 0, 0);
          acc[1][tn] = __builtin_amdgcn_mfma_f32_16x16x32_bf16(A1.v, wf[tn][kk], acc[1][tn], 0, 0, 0);
        }
      }

#pragma unroll
      for (int mt = 0; mt < 2; ++mt)
#pragma unroll
        for (int tn = 0; tn < 6; ++tn)
#pragma unroll
          for (int i = 0; i < 4; ++i)
            red[wv][mt][tn][((lg << 2) + i) * 16 + lr] = acc[mt][tn][i];
      __syncthreads();

      int mt = bb >> 4;
      int nh = j4 >> 4;
      int rbase = (bb & 15) * 16 + (j4 & 15);
      float4 s[3];
#pragma unroll
      for (int g = 0; g < 3; ++g) {
        float4 a4 = make_float4(0.f, 0.f, 0.f, 0.f);
#pragma unroll
        for (int w = 0; w < 4; ++w) {
          float4 v = *reinterpret_cast<const float4*>(&red[w][mt][g * 2 + nh][rbase]);
          a4.x += v.x; a4.y += v.y; a4.z += v.z; a4.w += v.w;
        }
        s[g] = a4;
      }

      float hn[4];
      {
        float r0 = sigm(gir.x + s[0].x + bhr.x);
        float r1 = sigm(gir.y + s[0].y + bhr.y);
        float r2 = sigm(gir.z + s[0].z + bhr.z);
        float r3 = sigm(gir.w + s[0].w + bhr.w);
        float z0 = sigm(giz.x + s[1].x + bhz.x);
        float z1 = sigm(giz.y + s[1].y + bhz.y);
        float z2 = sigm(giz.z + s[1].z + bhz.z);
        float z3 = sigm(giz.w + s[1].w + bhz.w);
        float a0 = gin.x + r0 * (s[2].x + bhn.x);
        float a1 = gin.y + r1 * (s[2].y + bhn.y);
        float a2 = gin.z + r2 * (s[2].z + bhn.z);
        float a3 = gin.w + r3 * (s[2].w + bhn.w);
        float n0 = 2.f / (1.f + __expf(-2.f * a0)) - 1.f;
        float n1 = 2.f / (1.f + __expf(-2.f * a1)) - 1.f;
        float n2 = 2.f / (1.f + __expf(-2.f * a2)) - 1.f;
        float n3 = 2.f / (1.f + __expf(-2.f * a3)) - 1.f;
        hn[0] = (1.f - z0) * n0 + z0 * hp.x;
        hn[1] = (1.f - z1) * n1 + z1 * hp.y;
        hn[2] = (1.f - z2) * n2 + z2 * hp.z;
        hn[3] = (1.f - z3) * n3 + z3 * hp.w;
        hp = make_float4(hn[0], hn[1], hn[2], hn[3]);
      }

      u32 p0 = (u32)f2bf(hn[0]) | ((u32)f2bf(hn[1]) << 16);
      u32 p1 = (u32)f2bf(hn[2]) | ((u32)f2bf(hn[3]) << 16);
      u64 pv = (u64)p0 | ((u64)p1 << 32);

      // Hall t-major, agent-scope (intra-kernel consumers on other XCDs)
      __hip_atomic_store(reinterpret_cast<u64*>(Hall + (size_t)(t * B_ + bb) * H_ + j0 + j4),
                         pv, RLX, AGENT);
      if (t < T_ - 1) {
        __hip_atomic_store(reinterpret_cast<u64*>(hb16 + (size_t)nxt * (B_ * H_) + bb * H_ + j0 + j4),
                           pv, RLX, AGENT);
      } else {
        reinterpret_cast<float4*>(outTail + (size_t)bb * H_ + j0 + j4)[0] = hp;
      }
      __syncthreads();  // red reads done; vmcnt(0) drain -> Hall/h committed at L3
      if (tid == 0)
        __hip_atomic_store(&flags[bid * 16], (u32)(t + 1), RLX, AGENT);  // terminal: 128
    }
    return;
  }

  // ============ static logits GEMM workers, BK=128 + XOR swizzle ============
  int wid = bid - NREC;
  u16* As = (u16*)smem;                 // [128][128] u16 = 32768 B (swizzled layout)
  u16* Bs = (u16*)(smem + 32768);       // 32768 B
  float* pmh = (float*)(smem + 65536);  // [2][128]
  float* psh = (float*)(smem + 66560);  // [2][128]
  int wrow = (wv >> 1) << 6, wcol = (wv & 1) << 6;

  // staging geometry: thread -> row srow=tid>>4 (+16/issue), seg=tid&15 (16B chunk).
  // Inverse-swizzled SOURCE: fetch column chunk (seg ^ (srow&7)) so that the
  // LINEAR LDS write at [row][seg*16B] holds logical column (seg ^ (row&7)).
  int srow = tid >> 4;
  int sseg = (tid & 15) ^ (srow & 7);   // srow&7 invariant under +16/issue

  for (int tau = wid; tau < NTILES; tau += NWK) {
    int m = tau / NTN, n = tau - m * NTN;
    int target = 4 * (m + 1);
    if (tid < NREC) {
      while ((int)__hip_atomic_load(&flags[tid * 16], RLX, AGENT) < target)
        __builtin_amdgcn_s_sleep(96);
    }
    __syncthreads();

    int m0 = m << 7, n0 = n << 7;
    f32x4 acc[4][4];
#pragma unroll
    for (int mi = 0; mi < 4; ++mi)
#pragma unroll
      for (int ni = 0; ni < 4; ++ni) acc[mi][ni] = (f32x4){0.f, 0.f, 0.f, 0.f};

    const u16* gA = Hall + (size_t)(m0 + srow) * H_ + (sseg << 3);
    const u16* gB = Wout16 + (size_t)(n0 + srow) * H_ + (sseg << 3);
    u16* lA = As + (wv << 9);           // wave-uniform base (HW adds lane*16B)
    u16* lB = Bs + (wv << 9);

    for (int k0 = 0; k0 < H_; k0 += 128) {
#pragma unroll
      for (int i = 0; i < 8; ++i) {
        gload_lds16(gA + (size_t)i * 16 * H_ + k0, lA + i * 2048);
        gload_lds16(gB + (size_t)i * 16 * H_ + k0, lB + i * 2048);
      }
      __syncthreads();
#pragma unroll
      for (int kk = 0; kk < 4; ++kk) {
        bf16x8 a[4], b[4];
#pragma unroll
        for (int mi = 0; mi < 4; ++mi) {
          int row = wrow + (mi << 4) + lr;
          int col = ((kk << 5) + (lg << 3)) ^ ((row & 7) << 3);  // swizzled read
          a[mi] = *reinterpret_cast<const bf16x8*>(&As[row * 128 + col]);
        }
#pragma unroll
        for (int ni = 0; ni < 4; ++ni) {
          int row = wcol + (ni << 4) + lr;
          int col = ((kk << 5) + (lg << 3)) ^ ((row & 7) << 3);
          b[ni] = *reinterpret_cast<const bf16x8*>(&Bs[row * 128 + col]);
        }
#pragma unroll
        for (int mi = 0; mi < 4; ++mi)
#pragma unroll
          for (int ni = 0; ni < 4; ++ni)
            acc[mi][ni] = __builtin_amdgcn_mfma_f32_16x16x32_bf16(a[mi], b[ni], acc[mi][ni], 0, 0, 0);
      }
      __syncthreads();
    }

    float bv[4];
#pragma unroll
    for (int ni = 0; ni < 4; ++ni) bv[ni] = bout[n0 + wcol + (ni << 4) + lr];

#pragma unroll
    for (int mi = 0; mi < 4; ++mi) {
#pragma unroll
      for (int i = 0; i < 4; ++i) {
        int row = wrow + (mi << 4) + (lg << 2) + i;
        int r = m0 + row;                            // t-major row
        int rg = (r & 31) * T_ + (r >> 5);           // b-major output row
        float* crow = out + (size_t)rg * V_;
        float v[4];
#pragma unroll
        for (int ni = 0; ni < 4; ++ni) {
          v[ni] = acc[mi][ni][i] + bv[ni];
          crow[n0 + wcol + (ni << 4) + lr] = v[ni];  // plain: consumed by later kernel
        }
        float vm = fmaxf(fmaxf(v[0], v[1]), fmaxf(v[2], v[3]));
        vm = fmaxf(vm, __shfl_xor(vm, 1));
        vm = fmaxf(vm, __shfl_xor(vm, 2));
        vm = fmaxf(vm, __shfl_xor(vm, 4));
        vm = fmaxf(vm, __shfl_xor(vm, 8));
        float se = __expf(v[0] - vm) + __expf(v[1] - vm) +
                   __expf(v[2] - vm) + __expf(v[3] - vm);
        se += __shfl_xor(se, 1);
        se += __shfl_xor(se, 2);
        se += __shfl_xor(se, 4);
        se += __shfl_xor(se, 8);
        if (lr == 0) { pmh[(wv & 1) * 128 + row] = vm; psh[(wv & 1) * 128 + row] = se; }
      }
    }
    __syncthreads();
    if (tid < 128) {
      float m0v = pmh[tid], m1v = pmh[128 + tid];
      float M = fmaxf(m0v, m1v);
      float S = psh[tid] * __expf(m0v - M) + psh[128 + tid] * __expf(m1v - M);
      int r = m0 + tid;
      int rg = (r & 31) * T_ + (r >> 5);
      pM[(size_t)rg * NT_STRIDE + n] = M;
      pS[(size_t)rg * NT_STRIDE + n] = S;
    }
    __syncthreads();  // pmh/psh reads done before next tile's writes
  }
}

// ---------------- fused LSE combine + subtract (512 threads/row) ----------------
__global__ __launch_bounds__(512)
void lse_fused_kernel(const float* __restrict__ pM, const float* __restrict__ pS,
                      float* __restrict__ out) {
  int r = blockIdx.x;
  int tid = threadIdx.x, wv = tid >> 6, ln = tid & 63;
  float M = -3.0e38f, S = 0.f;
  if (tid < NTN) { M = pM[(size_t)r * NT_STRIDE + tid]; S = pS[(size_t)r * NT_STRIDE + tid]; }
#pragma unroll
  for (int o = 32; o; o >>= 1) {
    float Mo = __shfl_xor(M, o);
    float So = __shfl_xor(S, o);
    float Mn = fmaxf(M, Mo);
    S = S * __expf(M - Mn) + So * __expf(Mo - Mn);
    M = Mn;
  }
  __shared__ float tM[8], tS[8], lsh;
  if (ln == 0) { tM[wv] = M; tS[wv] = S; }
  __syncthreads();
  if (tid == 0) {
    float Mf = tM[0], Sf = tS[0];
    for (int w = 1; w < 8; ++w) {
      float Mn = fmaxf(Mf, tM[w]);
      Sf = Sf * __expf(Mf - Mn) + tS[w] * __expf(tM[w] - Mn);
      Mf = Mn;
    }
    lsh = Mf + __logf(Sf);
  }
  __syncthreads();
  float l = lsh;
  float4* p = reinterpret_cast<float4*>(out + (size_t)r * V_);
  for (int i = tid; i < V_ / 4; i += 512) {
    float4 v = p[i];
    v.x -= l; v.y -= l; v.z -= l; v.w -= l;
    p[i] = v;
  }
}

// ---------------- host ----------------
extern "C" void kernel_launch(void* const* d_in, const int* in_sizes, int n_in,
                              void* d_out, int out_size, void* d_ws, size_t ws_size,
                              hipStream_t stream) {
  const float* enc_h = (const float*)d_in[1];
  const int*   tgt   = (const int*)d_in[2];
  const float* emb   = (const float*)d_in[3];
  const float* Wih   = (const float*)d_in[4];
  const float* Whh   = (const float*)d_in[5];
  const float* bih   = (const float*)d_in[6];
  const float* bhh   = (const float*)d_in[7];
  const float* Wout  = (const float*)d_in[8];
  const float* bout  = (const float*)d_in[9];
  float* out = (float*)d_out;

  char* ws = (char*)d_ws;
  size_t off = 0;
  auto alloc = [&](size_t bytes) -> void* {
    void* p = ws + off;
    off = (off + bytes + 255) & ~(size_t)255;
    return p;
  };
  u32*  flags  = (u32*)alloc(4096);
  u16*  Wih16  = (u16*)alloc((size_t)3 * H_ * E_ * 2);
  u16*  Whh16  = (u16*)alloc((size_t)3 * H_ * H_ * 2);
  u16*  Wout16 = (u16*)alloc((size_t)V_ * H_ * 2);
  u16*  X16    = (u16*)alloc((size_t)NROW * E_ * 2);
  u16*  Hall   = (u16*)alloc((size_t)NROW * H_ * 2);
  u16*  hb16   = (u16*)alloc((size_t)2 * B_ * H_ * 2);
  float* Gi    = (float*)alloc((size_t)NROW * 3 * H_ * 4);
  float* pM    = (float*)alloc((size_t)NROW * NT_STRIDE * 4);
  float* pS    = (float*)alloc((size_t)NROW * NT_STRIDE * 4);

  hipMemsetAsync(flags, 0, 4096, stream);
  cast_bf16_kernel<<<1024, 256, 0, stream>>>(Wih, Wih16, 3 * H_ * E_ / 4);
  cast_bf16_kernel<<<1024, 256, 0, stream>>>(Whh, Whh16, 3 * H_ * H_ / 4);
  cast_bf16_kernel<<<2048, 256, 0, stream>>>(Wout, Wout16, V_ * H_ / 4);
  cast_bf16_kernel<<<32, 256, 0, stream>>>(enc_h, hb16, B_ * H_ / 4);  // h buffer 0
  embed_kernel<<<NROW / 2, 256, 0, stream>>>(tgt, emb, X16);

  // Gi = X @ W_ih^T + b_ih   (M=4096, N=3072, K=512)
  gemm_bt_kernel<<<(3 * H_ / 128) * 32, 256, 0, stream>>>(X16, Wih16, bih, Gi, E_, 3 * H_);

  // recur + overlapped logits GEMM (BK=128, swizzled LDS) in one dispatch
  mega_kernel<<<GRID_MEGA, 256, 0, stream>>>(Whh16, Gi, bhh, enc_h, hb16, Hall,
                                             Wout16, bout, out, pM, pS,
                                             out + BTV, flags);

  lse_fused_kernel<<<NROW, 512, 0, stream>>>(pM, pS, out);
}